// Round 6
// baseline (396.641 us; speedup 1.0000x reference)
//
#include <hip/hip_runtime.h>
#include <hip/hip_bf16.h>
#include <stdint.h>

typedef __bf16 bf16;
typedef __attribute__((ext_vector_type(8))) __bf16 bf16x8;
typedef __attribute__((ext_vector_type(4))) float f32x4;

// async global->LDS, 16B per lane. LDS dest is linear: wave base + lane*16.
#define GLD(g, l) __builtin_amdgcn_global_load_lds( \
    (const __attribute__((address_space(1))) void*)(g), \
    (__attribute__((address_space(3))) void*)(l), 16, 0, 0)

__device__ __forceinline__ f32x4 mfma16(bf16x8 a, bf16x8 b, f32x4 c) {
  return __builtin_amdgcn_mfma_f32_16x16x32_bf16(a, b, c, 0, 0, 0);
}

// ---------------------------------------------------------------------------
// Generic 32x32 LDS-tiled transpose over z slices, src dtype ST -> dst bf16.
// ---------------------------------------------------------------------------
template <typename ST>
__global__ void transpose_k(const ST* __restrict__ src, bf16* __restrict__ dst,
                            int sld, int dld, int sdiv, int sA, int sB, int dA, int dB)
{
  __shared__ bf16 t[32][33];
  const int z = blockIdx.z;
  const ST* s = src + (size_t)(z / sdiv) * sA + (size_t)(z % sdiv) * sB;
  bf16* d = dst + (size_t)(z / sdiv) * dA + (size_t)(z % sdiv) * dB;
  const int c0 = blockIdx.x * 32, r0 = blockIdx.y * 32;
  const int tx = threadIdx.x, ty = threadIdx.y;
#pragma unroll
  for (int i = 0; i < 32; i += 8)
    t[ty + i][tx] = (bf16)(float)s[(r0 + ty + i) * sld + c0 + tx];
  __syncthreads();
#pragma unroll
  for (int i = 0; i < 32; i += 8)
    d[(c0 + ty + i) * dld + r0 + tx] = t[tx][ty + i];
}

// ---------------------------------------------------------------------------
// Fused QKV projection, stacked-M: seg = blockIdx.y/64 picks (q,k,v).
// C[seg][8192,1024](bf16) = (A_seg(fp32) @ W_seg^T + b_seg) * cmul_seg
// 128x128 tile, BK=64. A: fp32 reg-staged -> cvt -> padded LDS (72/row).
// B: bf16 via GLD with XOR chunk swizzle (chunk c stored at c^(row&7)).
// grid: (8 n-blocks fast, 192 m-blocks). K=1024 fixed.
// ---------------------------------------------------------------------------
__global__ __launch_bounds__(256) void proj_qkv(
    const float* __restrict__ Aq, const float* __restrict__ Ak,
    const float* __restrict__ Av, const bf16* __restrict__ WT,  // [3][1024][1024]
    const float* __restrict__ bq, const float* __restrict__ bk,
    const float* __restrict__ bv, bf16* __restrict__ Cb,        // [3][8192][1024]
    float cscale)
{
  __shared__ bf16 sA[128 * 72];  // [m][k] padded
  __shared__ bf16 sB[128 * 64];  // [n][k] swizzled chunks
  const int tid = threadIdx.x;
  const int wave = tid >> 6, lane = tid & 63;
  const int lr = lane & 15, quad = lane >> 4, kq = quad * 8;
  const int n0 = blockIdx.x * 128;
  const int mseg = blockIdx.y * 128;
  const int seg = mseg >> 13;          // /8192
  const int m0 = mseg & 8191;
  const int wr = (wave >> 1) * 64, wc = (wave & 1) * 64;

  const float* A = (seg == 0) ? Aq : (seg == 1) ? Ak : Av;
  const float* bias = (seg == 0) ? bq : (seg == 1) ? bk : bv;
  const float cmul = (seg == 0) ? cscale : 1.0f;
  const bf16* Bt = WT + (size_t)seg * (1 << 20);
  bf16* C = Cb + (size_t)seg * (8192 * 1024);

  f32x4 acc[4][4];
#pragma unroll
  for (int i = 0; i < 4; i++)
#pragma unroll
    for (int j = 0; j < 4; j++)
#pragma unroll
      for (int e = 0; e < 4; e++) acc[i][j][e] = 0.f;

  // A staging: lane covers row=tid>>1, 32 cols at half=(tid&1)*32
  const int ar = tid >> 1, ach = (tid & 1) * 32;
  const float* aPtr = A + (size_t)(m0 + ar) * 1024 + ach;
  // B staging via GLD: LDS chunk (tid per 4KB batch) -> row=tid>>3 (+32*batch),
  // stored position p=tid&7 holds logical chunk c = p ^ (row&7)
  const int brow = tid >> 3;
  const int bc = ((tid & 7) ^ (brow & 7)) * 8;
  const bf16* bPtr = Bt + (size_t)(n0 + brow) * 1024 + bc;
  bf16* sBd = sB + tid * 8;

  for (int k0 = 0; k0 < 1024; k0 += 64) {
    GLD(bPtr + k0,             sBd);
    GLD(bPtr + 32 * 1024 + k0, sBd + 2048);
    GLD(bPtr + 64 * 1024 + k0, sBd + 4096);
    GLD(bPtr + 96 * 1024 + k0, sBd + 6144);
    float4 f[8];
#pragma unroll
    for (int j = 0; j < 8; j++) f[j] = *(const float4*)(aPtr + k0 + j * 4);
    __syncthreads();  // prev-iter LDS reads done before overwrite
#pragma unroll
    for (int j = 0; j < 4; j++) {
      bf16x8 p;
      p[0] = (bf16)f[2*j].x; p[1] = (bf16)f[2*j].y;
      p[2] = (bf16)f[2*j].z; p[3] = (bf16)f[2*j].w;
      p[4] = (bf16)f[2*j+1].x; p[5] = (bf16)f[2*j+1].y;
      p[6] = (bf16)f[2*j+1].z; p[7] = (bf16)f[2*j+1].w;
      *(bf16x8*)(sA + ar * 72 + ach + j * 8) = p;
    }
    __syncthreads();
#pragma unroll
    for (int kk = 0; kk < 64; kk += 32) {
      bf16x8 af[4], bfr[4];
#pragma unroll
      for (int i = 0; i < 4; i++)
        af[i] = *(const bf16x8*)(sA + (wr + i * 16 + lr) * 72 + kk + kq);
#pragma unroll
      for (int i = 0; i < 4; i++) {
        const int pos = (((kk >> 3) + quad) ^ (lr & 7)) * 8;
        bfr[i] = *(const bf16x8*)(sB + (wc + i * 16 + lr) * 64 + pos);
      }
#pragma unroll
      for (int im = 0; im < 4; im++)
#pragma unroll
        for (int in = 0; in < 4; in++)
          acc[im][in] = mfma16(af[im], bfr[in], acc[im][in]);
    }
  }
  __syncthreads();

  const int qd = quad * 4;
  float bv4[4];
#pragma unroll
  for (int in = 0; in < 4; in++) bv4[in] = bias[n0 + wc + in * 16 + lr];
#pragma unroll
  for (int im = 0; im < 4; im++) {
    const int row = m0 + wr + im * 16 + qd;
#pragma unroll
    for (int in = 0; in < 4; in++) {
      const int col = n0 + wc + in * 16 + lr;
#pragma unroll
      for (int i = 0; i < 4; i++)
        C[(size_t)(row + i) * 1024 + col] = (bf16)((acc[im][in][i] + bv4[in]) * cmul);
    }
  }
}

// ---------------------------------------------------------------------------
// Final GEMM: C[8192,1024](fp32) = A(bf16) @ Bt^T + bias. BK=64, both
// operands GLD-staged with XOR chunk swizzle. grid (8 n fast, 64 m).
// ---------------------------------------------------------------------------
__global__ __launch_bounds__(256) void gemm_a16_c32(
    const bf16* __restrict__ A, const bf16* __restrict__ Bt,
    const float* __restrict__ bias, float* __restrict__ C)
{
  __shared__ bf16 sA[128 * 64];
  __shared__ bf16 sB[128 * 64];
  const int tid = threadIdx.x;
  const int wave = tid >> 6, lane = tid & 63;
  const int lr = lane & 15, quad = lane >> 4, kq = quad * 8;
  const int m0 = blockIdx.y * 128, n0 = blockIdx.x * 128;
  const int wr = (wave >> 1) * 64, wc = (wave & 1) * 64;

  f32x4 acc[4][4];
#pragma unroll
  for (int i = 0; i < 4; i++)
#pragma unroll
    for (int j = 0; j < 4; j++)
#pragma unroll
      for (int e = 0; e < 4; e++) acc[i][j][e] = 0.f;

  const int srow = tid >> 3;
  const int sc = ((tid & 7) ^ (srow & 7)) * 8;
  const bf16* aPtr = A + (size_t)(m0 + srow) * 1024 + sc;
  const bf16* bPtr = Bt + (size_t)(n0 + srow) * 1024 + sc;
  bf16* sAd = sA + tid * 8;
  bf16* sBd = sB + tid * 8;

  for (int k0 = 0; k0 < 1024; k0 += 64) {
    GLD(aPtr + k0,             sAd);
    GLD(aPtr + 32 * 1024 + k0, sAd + 2048);
    GLD(aPtr + 64 * 1024 + k0, sAd + 4096);
    GLD(aPtr + 96 * 1024 + k0, sAd + 6144);
    GLD(bPtr + k0,             sBd);
    GLD(bPtr + 32 * 1024 + k0, sBd + 2048);
    GLD(bPtr + 64 * 1024 + k0, sBd + 4096);
    GLD(bPtr + 96 * 1024 + k0, sBd + 6144);
    __syncthreads();
#pragma unroll
    for (int kk = 0; kk < 64; kk += 32) {
      bf16x8 af[4], bfr[4];
#pragma unroll
      for (int i = 0; i < 4; i++) {
        const int pos = (((kk >> 3) + quad) ^ (lr & 7)) * 8;
        af[i]  = *(const bf16x8*)(sA + (wr + i * 16 + lr) * 64 + pos);
        bfr[i] = *(const bf16x8*)(sB + (wc + i * 16 + lr) * 64 + pos);
      }
#pragma unroll
      for (int im = 0; im < 4; im++)
#pragma unroll
        for (int in = 0; in < 4; in++)
          acc[im][in] = mfma16(af[im], bfr[in], acc[im][in]);
    }
    __syncthreads();
  }

  const int qd = quad * 4;
  float bv4[4];
#pragma unroll
  for (int in = 0; in < 4; in++) bv4[in] = bias[n0 + wc + in * 16 + lr];
#pragma unroll
  for (int im = 0; im < 4; im++) {
    const int row = m0 + wr + im * 16 + qd;
#pragma unroll
    for (int in = 0; in < 4; in++) {
      const int col = n0 + wc + in * 16 + lr;
#pragma unroll
      for (int i = 0; i < 4; i++)
        C[(size_t)(row + i) * 1024 + col] = acc[im][in][i] + bv4[in];
    }
  }
}

// ---------------------------------------------------------------------------
// Flash attention per (b,h) — unchanged from round 5 (84 us, proven).
// Q pre-scaled by (1/8)*log2(e). No running max (logits bounded).
// LDS rows padded to 72. grid: (16 h, 8 b, 8 qtile), 256 threads.
// ---------------------------------------------------------------------------
__global__ __launch_bounds__(256) void attn_k(
    const bf16* __restrict__ Q, const bf16* __restrict__ Kh,
    const bf16* __restrict__ Vt, bf16* __restrict__ O)
{
  __shared__ bf16 sK[64 * 72];
  __shared__ bf16 sV[64 * 72];
  __shared__ bf16 sP[128 * 72];
  const int h = blockIdx.x, b = blockIdx.y, q0 = blockIdx.z * 128;
  const int tid = threadIdx.x, wave = tid >> 6, lane = tid & 63;
  const int lr = lane & 15, quad = lane >> 4, kq = quad * 8;
  const int wq = wave * 32;

  const bf16* Qb = Q + (size_t)(b * 1024 + q0) * 1024 + h * 64;
  const bf16* Kb = Kh + (size_t)(b * 1024) * 1024 + h * 64;
  const bf16* Vb = Vt + (size_t)(b * 16 + h) * 65536;

  bf16x8 qf[2][2];
#pragma unroll
  for (int rg = 0; rg < 2; rg++)
#pragma unroll
    for (int ks = 0; ks < 2; ks++)
      qf[rg][ks] = *(const bf16x8*)(Qb + (wq + rg * 16 + lr) * 1024 + ks * 32 + kq);

  f32x4 o[2][4];
  float rsum[2][4];
#pragma unroll
  for (int rg = 0; rg < 2; rg++) {
#pragma unroll
    for (int et = 0; et < 4; et++)
#pragma unroll
      for (int e = 0; e < 4; e++) o[rg][et][e] = 0.f;
#pragma unroll
    for (int i = 0; i < 4; i++) rsum[rg][i] = 0.f;
  }

  const int r = tid >> 3;
  const int c = (tid & 7) * 8;

  for (int kv0 = 0; kv0 < 1024; kv0 += 64) {
    bf16x8 k1 = *(const bf16x8*)(Kb + (size_t)(kv0 + r) * 1024 + c);
    bf16x8 k2 = *(const bf16x8*)(Kb + (size_t)(kv0 + 32 + r) * 1024 + c);
    bf16x8 v1 = *(const bf16x8*)(Vb + (size_t)r * 1024 + kv0 + c);
    bf16x8 v2 = *(const bf16x8*)(Vb + (size_t)(32 + r) * 1024 + kv0 + c);
    __syncthreads();
    *(bf16x8*)(sK + r * 72 + c) = k1;
    *(bf16x8*)(sK + (32 + r) * 72 + c) = k2;
    *(bf16x8*)(sV + r * 72 + c) = v1;
    *(bf16x8*)(sV + (32 + r) * 72 + c) = v2;
    __syncthreads();

    f32x4 sc[2][4];
#pragma unroll
    for (int nt = 0; nt < 4; nt++) {
      bf16x8 kf0 = *(const bf16x8*)(sK + (nt * 16 + lr) * 72 + kq);
      bf16x8 kf1 = *(const bf16x8*)(sK + (nt * 16 + lr) * 72 + 32 + kq);
#pragma unroll
      for (int rg = 0; rg < 2; rg++) {
        f32x4 z;
#pragma unroll
        for (int e = 0; e < 4; e++) z[e] = 0.f;
        z = mfma16(qf[rg][0], kf0, z);
        z = mfma16(qf[rg][1], kf1, z);
        sc[rg][nt] = z;
      }
    }

#pragma unroll
    for (int rg = 0; rg < 2; rg++)
#pragma unroll
      for (int i = 0; i < 4; i++) {
        float p0 = exp2f(sc[rg][0][i]);
        float p1 = exp2f(sc[rg][1][i]);
        float p2 = exp2f(sc[rg][2][i]);
        float p3 = exp2f(sc[rg][3][i]);
        rsum[rg][i] += (p0 + p1) + (p2 + p3);
        const int prow = (wq + rg * 16 + quad * 4 + i) * 72;
        sP[prow + 0 * 16 + lr] = (bf16)p0;
        sP[prow + 1 * 16 + lr] = (bf16)p1;
        sP[prow + 2 * 16 + lr] = (bf16)p2;
        sP[prow + 3 * 16 + lr] = (bf16)p3;
      }
    __syncthreads();

#pragma unroll
    for (int et = 0; et < 4; et++) {
      bf16x8 vf0 = *(const bf16x8*)(sV + (et * 16 + lr) * 72 + kq);
      bf16x8 vf1 = *(const bf16x8*)(sV + (et * 16 + lr) * 72 + 32 + kq);
#pragma unroll
      for (int rg = 0; rg < 2; rg++) {
        bf16x8 pa = *(const bf16x8*)(sP + (wq + rg * 16 + lr) * 72 + kq);
        bf16x8 pb = *(const bf16x8*)(sP + (wq + rg * 16 + lr) * 72 + 32 + kq);
        o[rg][et] = mfma16(pa, vf0, o[rg][et]);
        o[rg][et] = mfma16(pb, vf1, o[rg][et]);
      }
    }
  }

#pragma unroll
  for (int rg = 0; rg < 2; rg++)
#pragma unroll
    for (int i = 0; i < 4; i++) {
      float rs = rsum[rg][i];
#pragma unroll
      for (int off = 1; off < 16; off <<= 1)
        rs += __shfl_xor(rs, off, 64);
      rsum[rg][i] = 1.f / rs;
    }

  bf16* Ob = O + (size_t)(b * 1024 + q0) * 1024 + h * 64;
#pragma unroll
  for (int rg = 0; rg < 2; rg++)
#pragma unroll
    for (int i = 0; i < 4; i++) {
      const int row = wq + rg * 16 + quad * 4 + i;
#pragma unroll
      for (int et = 0; et < 4; et++)
        Ob[row * 1024 + et * 16 + lr] = (bf16)(o[rg][et][i] * rsum[rg][i]);
    }
}

// ---------------------------------------------------------------------------
extern "C" void kernel_launch(void* const* d_in, const int* in_sizes, int n_in,
                              void* d_out, int out_size, void* d_ws, size_t ws_size,
                              hipStream_t stream)
{
  const float* q  = (const float*)d_in[0];
  const float* k  = (const float*)d_in[1];
  const float* v  = (const float*)d_in[2];
  const float* Wq = (const float*)d_in[3];
  const float* bq = (const float*)d_in[4];
  const float* Wk = (const float*)d_in[5];
  const float* bk = (const float*)d_in[6];
  const float* Wv = (const float*)d_in[7];
  const float* bv = (const float*)d_in[8];
  const float* Wo = (const float*)d_in[9];
  const float* bo = (const float*)d_in[10];
  float* out = (float*)d_out;
  bf16* ws = (bf16*)d_ws;

  const int MB = 1 << 20;
  bf16* WT  = ws;              // [3][1024][1024] bf16: WqT,WkT,WvT contiguous
  bf16* WoT = ws + 3 * MB;
  bf16* qkv = ws + 4 * MB;     // [3][8192][1024] bf16: qh,kh,vh contiguous
  bf16* qh  = qkv;
  bf16* kh  = qkv + 8 * MB;
  bf16* vh  = qkv + 16 * MB;   // ws total 56 MB
  bf16* vt  = (bf16*)d_out;    // 16 MB scratch in the 32 MB fp32 out buffer
  bf16* ctx = vh;              // vh dead after vt transpose

  const float cscale = 0.1803368801111601f;  // (1/8)*log2(e)

  dim3 tb(32, 8);
  transpose_k<float><<<dim3(2, 32, 16), tb, 0, stream>>>(Wq, WT,          64, 1024, 16, 0, 65536, 0, 65536);
  transpose_k<float><<<dim3(2, 32, 16), tb, 0, stream>>>(Wk, WT + 1 * MB, 64, 1024, 16, 0, 65536, 0, 65536);
  transpose_k<float><<<dim3(2, 32, 16), tb, 0, stream>>>(Wv, WT + 2 * MB, 64, 1024, 16, 0, 65536, 0, 65536);
  transpose_k<float><<<dim3(32, 32, 1), tb, 0, stream>>>(Wo, WoT, 1024, 1024, 1, 0, 0, 0, 0);

  // fused q/k/v projection: one dispatch, cast folded into A staging
  proj_qkv<<<dim3(8, 192), 256, 0, stream>>>(q, k, v, WT, bq, bk, bv, qkv, cscale);

  // vh[(b*1024+s), h*64+e] -> vt[(b*16+h)*65536 + e*1024 + s]
  transpose_k<bf16><<<dim3(2, 32, 128), tb, 0, stream>>>(vh, vt, 1024, 1024, 16,
                                                         1048576, 64, 1048576, 65536);

  attn_k<<<dim3(16, 8, 8), 256, 0, stream>>>(qh, kh, vt, ctx);

  // out(fp32) = ctx @ Wo + bo
  gemm_a16_c32<<<dim3(8, 64), 256, 0, stream>>>(ctx, WoT, bo, out);
}

// Round 7
// 374.538 us; speedup vs baseline: 1.0590x; 1.0590x over previous
//
#include <hip/hip_runtime.h>
#include <hip/hip_bf16.h>
#include <stdint.h>

typedef __bf16 bf16;
typedef __attribute__((ext_vector_type(8))) __bf16 bf16x8;
typedef __attribute__((ext_vector_type(4))) float f32x4;

// async global->LDS, 16B per lane. LDS dest is linear: wave base + lane*16.
#define GLD(g, l) __builtin_amdgcn_global_load_lds( \
    (const __attribute__((address_space(1))) void*)(g), \
    (__attribute__((address_space(3))) void*)(l), 16, 0, 0)

__device__ __forceinline__ f32x4 mfma16(bf16x8 a, bf16x8 b, f32x4 c) {
  return __builtin_amdgcn_mfma_f32_16x16x32_bf16(a, b, c, 0, 0, 0);
}

// ---------------------------------------------------------------------------
// Generic 32x32 LDS-tiled transpose over z slices, src dtype ST -> dst bf16.
// ---------------------------------------------------------------------------
template <typename ST>
__global__ void transpose_k(const ST* __restrict__ src, bf16* __restrict__ dst,
                            int sld, int dld, int sdiv, int sA, int sB, int dA, int dB)
{
  __shared__ bf16 t[32][33];
  const int z = blockIdx.z;
  const ST* s = src + (size_t)(z / sdiv) * sA + (size_t)(z % sdiv) * sB;
  bf16* d = dst + (size_t)(z / sdiv) * dA + (size_t)(z % sdiv) * dB;
  const int c0 = blockIdx.x * 32, r0 = blockIdx.y * 32;
  const int tx = threadIdx.x, ty = threadIdx.y;
#pragma unroll
  for (int i = 0; i < 32; i += 8)
    t[ty + i][tx] = (bf16)(float)s[(r0 + ty + i) * sld + c0 + tx];
  __syncthreads();
#pragma unroll
  for (int i = 0; i < 32; i += 8)
    d[(c0 + ty + i) * dld + r0 + tx] = t[tx][ty + i];
}

// ---------------------------------------------------------------------------
// Fused QKV projection, stacked-M: seg picks (q,k,v).
// grid: (192 m-blocks FAST, 8 n-blocks). 192%8==0 -> all 8 n-blocks of one
// m-stripe share linear%8 -> same XCD -> fp32 A-stripe (512KB) hits L2 8x.
// (Round-6 n-fast grid spread them over 8 XCDs: FETCH=398MB, HBM-bound.)
// 128x128 tile, BK=64. A: fp32 reg-staged -> cvt -> padded LDS (72/row).
// B: bf16 via GLD with XOR chunk swizzle (chunk c stored at c^(row&7)).
// ---------------------------------------------------------------------------
__global__ __launch_bounds__(256) void proj_qkv(
    const float* __restrict__ Aq, const float* __restrict__ Ak,
    const float* __restrict__ Av, const bf16* __restrict__ WT,  // [3][1024][1024]
    const float* __restrict__ bq, const float* __restrict__ bk,
    const float* __restrict__ bv, bf16* __restrict__ Cb,        // [3][8192][1024]
    float cscale)
{
  __shared__ bf16 sA[128 * 72];  // [m][k] padded
  __shared__ bf16 sB[128 * 64];  // [n][k] swizzled chunks
  const int tid = threadIdx.x;
  const int wave = tid >> 6, lane = tid & 63;
  const int lr = lane & 15, quad = lane >> 4, kq = quad * 8;
  const int n0 = blockIdx.y * 128;          // n is the SLOW grid dim now
  const int mseg = blockIdx.x * 128;        // m fast -> same-XCD A reuse
  const int seg = mseg >> 13;               // /8192
  const int m0 = mseg & 8191;
  const int wr = (wave >> 1) * 64, wc = (wave & 1) * 64;

  const float* A = (seg == 0) ? Aq : (seg == 1) ? Ak : Av;
  const float* bias = (seg == 0) ? bq : (seg == 1) ? bk : bv;
  const float cmul = (seg == 0) ? cscale : 1.0f;
  const bf16* Bt = WT + (size_t)seg * (1 << 20);
  bf16* C = Cb + (size_t)seg * (8192 * 1024);

  f32x4 acc[4][4];
#pragma unroll
  for (int i = 0; i < 4; i++)
#pragma unroll
    for (int j = 0; j < 4; j++)
#pragma unroll
      for (int e = 0; e < 4; e++) acc[i][j][e] = 0.f;

  // A staging: lane covers row=tid>>1, 32 cols at half=(tid&1)*32
  const int ar = tid >> 1, ach = (tid & 1) * 32;
  const float* aPtr = A + (size_t)(m0 + ar) * 1024 + ach;
  // B staging via GLD: row=tid>>3 (+32/batch); stored pos p=tid&7 holds
  // logical chunk c = p ^ (row&7)
  const int brow = tid >> 3;
  const int bc = ((tid & 7) ^ (brow & 7)) * 8;
  const bf16* bPtr = Bt + (size_t)(n0 + brow) * 1024 + bc;
  bf16* sBd = sB + tid * 8;

  for (int k0 = 0; k0 < 1024; k0 += 64) {
    GLD(bPtr + k0,             sBd);
    GLD(bPtr + 32 * 1024 + k0, sBd + 2048);
    GLD(bPtr + 64 * 1024 + k0, sBd + 4096);
    GLD(bPtr + 96 * 1024 + k0, sBd + 6144);
    float4 f[8];
#pragma unroll
    for (int j = 0; j < 8; j++) f[j] = *(const float4*)(aPtr + k0 + j * 4);
    __syncthreads();  // prev-iter LDS reads done before overwrite
#pragma unroll
    for (int j = 0; j < 4; j++) {
      bf16x8 p;
      p[0] = (bf16)f[2*j].x; p[1] = (bf16)f[2*j].y;
      p[2] = (bf16)f[2*j].z; p[3] = (bf16)f[2*j].w;
      p[4] = (bf16)f[2*j+1].x; p[5] = (bf16)f[2*j+1].y;
      p[6] = (bf16)f[2*j+1].z; p[7] = (bf16)f[2*j+1].w;
      *(bf16x8*)(sA + ar * 72 + ach + j * 8) = p;
    }
    __syncthreads();
#pragma unroll
    for (int kk = 0; kk < 64; kk += 32) {
      bf16x8 af[4], bfr[4];
#pragma unroll
      for (int i = 0; i < 4; i++)
        af[i] = *(const bf16x8*)(sA + (wr + i * 16 + lr) * 72 + kk + kq);
#pragma unroll
      for (int i = 0; i < 4; i++) {
        const int pos = (((kk >> 3) + quad) ^ (lr & 7)) * 8;
        bfr[i] = *(const bf16x8*)(sB + (wc + i * 16 + lr) * 64 + pos);
      }
#pragma unroll
      for (int im = 0; im < 4; im++)
#pragma unroll
        for (int in = 0; in < 4; in++)
          acc[im][in] = mfma16(af[im], bfr[in], acc[im][in]);
    }
  }
  __syncthreads();

  const int qd = quad * 4;
  float bv4[4];
#pragma unroll
  for (int in = 0; in < 4; in++) bv4[in] = bias[n0 + wc + in * 16 + lr];
#pragma unroll
  for (int im = 0; im < 4; im++) {
    const int row = m0 + wr + im * 16 + qd;
#pragma unroll
    for (int in = 0; in < 4; in++) {
      const int col = n0 + wc + in * 16 + lr;
#pragma unroll
      for (int i = 0; i < 4; i++)
        C[(size_t)(row + i) * 1024 + col] = (bf16)((acc[im][in][i] + bv4[in]) * cmul);
    }
  }
}

// ---------------------------------------------------------------------------
// Final GEMM: C[8192,1024](fp32) = A(bf16) @ Bt^T + bias. BK=64, both
// operands GLD-staged with XOR chunk swizzle.
// grid (64 m FAST, 8 n): same-m blocks share XCD -> A-stripe L2 reuse;
// per-XCD working set A 2MB + B 2MB fits the 4MB L2.
// ---------------------------------------------------------------------------
__global__ __launch_bounds__(256) void gemm_a16_c32(
    const bf16* __restrict__ A, const bf16* __restrict__ Bt,
    const float* __restrict__ bias, float* __restrict__ C)
{
  __shared__ bf16 sA[128 * 64];
  __shared__ bf16 sB[128 * 64];
  const int tid = threadIdx.x;
  const int wave = tid >> 6, lane = tid & 63;
  const int lr = lane & 15, quad = lane >> 4, kq = quad * 8;
  const int m0 = blockIdx.x * 128, n0 = blockIdx.y * 128;
  const int wr = (wave >> 1) * 64, wc = (wave & 1) * 64;

  f32x4 acc[4][4];
#pragma unroll
  for (int i = 0; i < 4; i++)
#pragma unroll
    for (int j = 0; j < 4; j++)
#pragma unroll
      for (int e = 0; e < 4; e++) acc[i][j][e] = 0.f;

  const int srow = tid >> 3;
  const int sc = ((tid & 7) ^ (srow & 7)) * 8;
  const bf16* aPtr = A + (size_t)(m0 + srow) * 1024 + sc;
  const bf16* bPtr = Bt + (size_t)(n0 + srow) * 1024 + sc;
  bf16* sAd = sA + tid * 8;
  bf16* sBd = sB + tid * 8;

  for (int k0 = 0; k0 < 1024; k0 += 64) {
    GLD(aPtr + k0,             sAd);
    GLD(aPtr + 32 * 1024 + k0, sAd + 2048);
    GLD(aPtr + 64 * 1024 + k0, sAd + 4096);
    GLD(aPtr + 96 * 1024 + k0, sAd + 6144);
    GLD(bPtr + k0,             sBd);
    GLD(bPtr + 32 * 1024 + k0, sBd + 2048);
    GLD(bPtr + 64 * 1024 + k0, sBd + 4096);
    GLD(bPtr + 96 * 1024 + k0, sBd + 6144);
    __syncthreads();
#pragma unroll
    for (int kk = 0; kk < 64; kk += 32) {
      bf16x8 af[4], bfr[4];
#pragma unroll
      for (int i = 0; i < 4; i++) {
        const int pos = (((kk >> 3) + quad) ^ (lr & 7)) * 8;
        af[i]  = *(const bf16x8*)(sA + (wr + i * 16 + lr) * 64 + pos);
        bfr[i] = *(const bf16x8*)(sB + (wc + i * 16 + lr) * 64 + pos);
      }
#pragma unroll
      for (int im = 0; im < 4; im++)
#pragma unroll
        for (int in = 0; in < 4; in++)
          acc[im][in] = mfma16(af[im], bfr[in], acc[im][in]);
    }
    __syncthreads();
  }

  const int qd = quad * 4;
  float bv4[4];
#pragma unroll
  for (int in = 0; in < 4; in++) bv4[in] = bias[n0 + wc + in * 16 + lr];
#pragma unroll
  for (int im = 0; im < 4; im++) {
    const int row = m0 + wr + im * 16 + qd;
#pragma unroll
    for (int in = 0; in < 4; in++) {
      const int col = n0 + wc + in * 16 + lr;
#pragma unroll
      for (int i = 0; i < 4; i++)
        C[(size_t)(row + i) * 1024 + col] = acc[im][in][i] + bv4[in];
    }
  }
}

// ---------------------------------------------------------------------------
// Flash attention per (b,h) — unchanged (84 us, proven).
// Q pre-scaled by (1/8)*log2(e). No running max (logits bounded).
// LDS rows padded to 72. grid: (16 h, 8 b, 8 qtile), 256 threads.
// ---------------------------------------------------------------------------
__global__ __launch_bounds__(256) void attn_k(
    const bf16* __restrict__ Q, const bf16* __restrict__ Kh,
    const bf16* __restrict__ Vt, bf16* __restrict__ O)
{
  __shared__ bf16 sK[64 * 72];
  __shared__ bf16 sV[64 * 72];
  __shared__ bf16 sP[128 * 72];
  const int h = blockIdx.x, b = blockIdx.y, q0 = blockIdx.z * 128;
  const int tid = threadIdx.x, wave = tid >> 6, lane = tid & 63;
  const int lr = lane & 15, quad = lane >> 4, kq = quad * 8;
  const int wq = wave * 32;

  const bf16* Qb = Q + (size_t)(b * 1024 + q0) * 1024 + h * 64;
  const bf16* Kb = Kh + (size_t)(b * 1024) * 1024 + h * 64;
  const bf16* Vb = Vt + (size_t)(b * 16 + h) * 65536;

  bf16x8 qf[2][2];
#pragma unroll
  for (int rg = 0; rg < 2; rg++)
#pragma unroll
    for (int ks = 0; ks < 2; ks++)
      qf[rg][ks] = *(const bf16x8*)(Qb + (wq + rg * 16 + lr) * 1024 + ks * 32 + kq);

  f32x4 o[2][4];
  float rsum[2][4];
#pragma unroll
  for (int rg = 0; rg < 2; rg++) {
#pragma unroll
    for (int et = 0; et < 4; et++)
#pragma unroll
      for (int e = 0; e < 4; e++) o[rg][et][e] = 0.f;
#pragma unroll
    for (int i = 0; i < 4; i++) rsum[rg][i] = 0.f;
  }

  const int r = tid >> 3;
  const int c = (tid & 7) * 8;

  for (int kv0 = 0; kv0 < 1024; kv0 += 64) {
    bf16x8 k1 = *(const bf16x8*)(Kb + (size_t)(kv0 + r) * 1024 + c);
    bf16x8 k2 = *(const bf16x8*)(Kb + (size_t)(kv0 + 32 + r) * 1024 + c);
    bf16x8 v1 = *(const bf16x8*)(Vb + (size_t)r * 1024 + kv0 + c);
    bf16x8 v2 = *(const bf16x8*)(Vb + (size_t)(32 + r) * 1024 + kv0 + c);
    __syncthreads();
    *(bf16x8*)(sK + r * 72 + c) = k1;
    *(bf16x8*)(sK + (32 + r) * 72 + c) = k2;
    *(bf16x8*)(sV + r * 72 + c) = v1;
    *(bf16x8*)(sV + (32 + r) * 72 + c) = v2;
    __syncthreads();

    f32x4 sc[2][4];
#pragma unroll
    for (int nt = 0; nt < 4; nt++) {
      bf16x8 kf0 = *(const bf16x8*)(sK + (nt * 16 + lr) * 72 + kq);
      bf16x8 kf1 = *(const bf16x8*)(sK + (nt * 16 + lr) * 72 + 32 + kq);
#pragma unroll
      for (int rg = 0; rg < 2; rg++) {
        f32x4 z;
#pragma unroll
        for (int e = 0; e < 4; e++) z[e] = 0.f;
        z = mfma16(qf[rg][0], kf0, z);
        z = mfma16(qf[rg][1], kf1, z);
        sc[rg][nt] = z;
      }
    }

#pragma unroll
    for (int rg = 0; rg < 2; rg++)
#pragma unroll
      for (int i = 0; i < 4; i++) {
        float p0 = exp2f(sc[rg][0][i]);
        float p1 = exp2f(sc[rg][1][i]);
        float p2 = exp2f(sc[rg][2][i]);
        float p3 = exp2f(sc[rg][3][i]);
        rsum[rg][i] += (p0 + p1) + (p2 + p3);
        const int prow = (wq + rg * 16 + quad * 4 + i) * 72;
        sP[prow + 0 * 16 + lr] = (bf16)p0;
        sP[prow + 1 * 16 + lr] = (bf16)p1;
        sP[prow + 2 * 16 + lr] = (bf16)p2;
        sP[prow + 3 * 16 + lr] = (bf16)p3;
      }
    __syncthreads();

#pragma unroll
    for (int et = 0; et < 4; et++) {
      bf16x8 vf0 = *(const bf16x8*)(sV + (et * 16 + lr) * 72 + kq);
      bf16x8 vf1 = *(const bf16x8*)(sV + (et * 16 + lr) * 72 + 32 + kq);
#pragma unroll
      for (int rg = 0; rg < 2; rg++) {
        bf16x8 pa = *(const bf16x8*)(sP + (wq + rg * 16 + lr) * 72 + kq);
        bf16x8 pb = *(const bf16x8*)(sP + (wq + rg * 16 + lr) * 72 + 32 + kq);
        o[rg][et] = mfma16(pa, vf0, o[rg][et]);
        o[rg][et] = mfma16(pb, vf1, o[rg][et]);
      }
    }
  }

#pragma unroll
  for (int rg = 0; rg < 2; rg++)
#pragma unroll
    for (int i = 0; i < 4; i++) {
      float rs = rsum[rg][i];
#pragma unroll
      for (int off = 1; off < 16; off <<= 1)
        rs += __shfl_xor(rs, off, 64);
      rsum[rg][i] = 1.f / rs;
    }

  bf16* Ob = O + (size_t)(b * 1024 + q0) * 1024 + h * 64;
#pragma unroll
  for (int rg = 0; rg < 2; rg++)
#pragma unroll
    for (int i = 0; i < 4; i++) {
      const int row = wq + rg * 16 + quad * 4 + i;
#pragma unroll
      for (int et = 0; et < 4; et++)
        Ob[row * 1024 + et * 16 + lr] = (bf16)(o[rg][et][i] * rsum[rg][i]);
    }
}

// ---------------------------------------------------------------------------
extern "C" void kernel_launch(void* const* d_in, const int* in_sizes, int n_in,
                              void* d_out, int out_size, void* d_ws, size_t ws_size,
                              hipStream_t stream)
{
  const float* q  = (const float*)d_in[0];
  const float* k  = (const float*)d_in[1];
  const float* v  = (const float*)d_in[2];
  const float* Wq = (const float*)d_in[3];
  const float* bq = (const float*)d_in[4];
  const float* Wk = (const float*)d_in[5];
  const float* bk = (const float*)d_in[6];
  const float* Wv = (const float*)d_in[7];
  const float* bv = (const float*)d_in[8];
  const float* Wo = (const float*)d_in[9];
  const float* bo = (const float*)d_in[10];
  float* out = (float*)d_out;
  bf16* ws = (bf16*)d_ws;

  const int MB = 1 << 20;
  bf16* WT  = ws;              // [3][1024][1024] bf16: WqT,WkT,WvT contiguous
  bf16* WoT = ws + 3 * MB;
  bf16* qkv = ws + 4 * MB;     // [3][8192][1024] bf16: qh,kh,vh contiguous
  bf16* qh  = qkv;
  bf16* kh  = qkv + 8 * MB;
  bf16* vh  = qkv + 16 * MB;   // ws total 56 MB
  bf16* vt  = (bf16*)d_out;    // 16 MB scratch in the 32 MB fp32 out buffer
  bf16* ctx = vh;              // vh dead after vt transpose

  const float cscale = 0.1803368801111601f;  // (1/8)*log2(e)

  dim3 tb(32, 8);
  transpose_k<float><<<dim3(2, 32, 16), tb, 0, stream>>>(Wq, WT,          64, 1024, 16, 0, 65536, 0, 65536);
  transpose_k<float><<<dim3(2, 32, 16), tb, 0, stream>>>(Wk, WT + 1 * MB, 64, 1024, 16, 0, 65536, 0, 65536);
  transpose_k<float><<<dim3(2, 32, 16), tb, 0, stream>>>(Wv, WT + 2 * MB, 64, 1024, 16, 0, 65536, 0, 65536);
  transpose_k<float><<<dim3(32, 32, 1), tb, 0, stream>>>(Wo, WoT, 1024, 1024, 1, 0, 0, 0, 0);

  // fused q/k/v projection: m-fast grid for same-XCD A-stripe reuse
  proj_qkv<<<dim3(192, 8), 256, 0, stream>>>(q, k, v, WT, bq, bk, bv, qkv, cscale);

  // vh[(b*1024+s), h*64+e] -> vt[(b*16+h)*65536 + e*1024 + s]
  transpose_k<bf16><<<dim3(2, 32, 128), tb, 0, stream>>>(vh, vt, 1024, 1024, 16,
                                                         1048576, 64, 1048576, 65536);

  attn_k<<<dim3(16, 8, 8), 256, 0, stream>>>(qh, kh, vt, ctx);

  // out(fp32) = ctx @ Wo + bo
  gemm_a16_c32<<<dim3(64, 8), 256, 0, stream>>>(ctx, WoT, bo, out);
}

// Round 8
// 362.906 us; speedup vs baseline: 1.0930x; 1.0320x over previous
//
#include <hip/hip_runtime.h>
#include <hip/hip_bf16.h>
#include <stdint.h>

typedef __bf16 bf16;
typedef __attribute__((ext_vector_type(8))) __bf16 bf16x8;
typedef __attribute__((ext_vector_type(4))) __bf16 bf16x4;
typedef __attribute__((ext_vector_type(4))) float f32x4;

// async global->LDS, 16B per lane. LDS dest is linear: wave base + lane*16.
#define GLD(g, l) __builtin_amdgcn_global_load_lds( \
    (const __attribute__((address_space(1))) void*)(g), \
    (__attribute__((address_space(3))) void*)(l), 16, 0, 0)

__device__ __forceinline__ f32x4 mfma16(bf16x8 a, bf16x8 b, f32x4 c) {
  return __builtin_amdgcn_mfma_f32_16x16x32_bf16(a, b, c, 0, 0, 0);
}

// ---------------------------------------------------------------------------
// Fused per-head weight transpose: W{q,k,v}[h][1024 d][64 e](fp32) ->
// WT[w][(h*64+e)][d](bf16). grid (32,32,3): x = h*2+xblk, y = d-tile, z = w.
// ---------------------------------------------------------------------------
__global__ void wtrans3(const float* __restrict__ Wq, const float* __restrict__ Wk,
                        const float* __restrict__ Wv, bf16* __restrict__ WT)
{
  __shared__ bf16 t[32][33];
  const int w = blockIdx.z;
  const float* W = (w == 0) ? Wq : (w == 1) ? Wk : Wv;
  const int h = blockIdx.x >> 1;
  const int c0 = (blockIdx.x & 1) * 32;   // e
  const int r0 = blockIdx.y * 32;         // d
  const float* s = W + (size_t)h * 65536;
  bf16* d = WT + (size_t)w * (1 << 20) + (size_t)h * 65536;
  const int tx = threadIdx.x, ty = threadIdx.y;
#pragma unroll
  for (int i = 0; i < 32; i += 8)
    t[ty + i][tx] = (bf16)s[(r0 + ty + i) * 64 + c0 + tx];
  __syncthreads();
#pragma unroll
  for (int i = 0; i < 32; i += 8)
    d[(c0 + ty + i) * 1024 + r0 + tx] = t[tx][ty + i];
}

// ---------------------------------------------------------------------------
// Wo[k,n](fp32) -> WoT[n,k](bf16). grid (32,32), block (32,8).
// ---------------------------------------------------------------------------
__global__ void wtransO(const float* __restrict__ src, bf16* __restrict__ dst)
{
  __shared__ bf16 t[32][33];
  const int c0 = blockIdx.x * 32, r0 = blockIdx.y * 32;
  const int tx = threadIdx.x, ty = threadIdx.y;
#pragma unroll
  for (int i = 0; i < 32; i += 8)
    t[ty + i][tx] = (bf16)src[(r0 + ty + i) * 1024 + c0 + tx];
  __syncthreads();
#pragma unroll
  for (int i = 0; i < 32; i += 8)
    dst[(c0 + ty + i) * 1024 + r0 + tx] = t[tx][ty + i];
}

// ---------------------------------------------------------------------------
// fp32 -> bf16 cast for q and k in one dispatch. grid (4096, 2).
// ---------------------------------------------------------------------------
__global__ __launch_bounds__(256) void cast2(const float* __restrict__ q,
                                             const float* __restrict__ k,
                                             bf16* __restrict__ qc,
                                             bf16* __restrict__ kc)
{
  const float* s = blockIdx.y ? k : q;
  bf16* d = blockIdx.y ? kc : qc;
  const size_t i = ((size_t)blockIdx.x * 256 + threadIdx.x) * 8;
  float4 a = *(const float4*)(s + i);
  float4 b = *(const float4*)(s + i + 4);
  bf16x8 p;
  p[0] = (bf16)a.x; p[1] = (bf16)a.y; p[2] = (bf16)a.z; p[3] = (bf16)a.w;
  p[4] = (bf16)b.x; p[5] = (bf16)b.y; p[6] = (bf16)b.z; p[7] = (bf16)b.w;
  *(bf16x8*)(d + i) = p;
}

// ---------------------------------------------------------------------------
// Fused QKV projection, stacked-M (seg = q/k/v), 128x128 tile, BK=64,
// XOR chunk swizzle (chunk c of row r at position c^(r&7)).
// seg 0/1: A = qc/kc (bf16) via GLD (pure m97-style 2-barrier loop).
// seg 2:   A = v (fp32) reg-staged+cvt; GLD(B) issued after barrier #1
//          (fixes round-7 latent race of GLD(B) vs prev-iter sB reads).
// seg 0/1 epilogue -> qh/kh row-major (qh scaled by cscale);
// seg 2 epilogue   -> vt[(b*16+h)*65536 + e*1024 + s] directly (bf16x4,
//          s-contiguous) — eliminates the separate V-transpose dispatch.
// grid (192 m-fast, 8 n): same-stripe blocks share XCD for A L2 reuse.
// ---------------------------------------------------------------------------
__global__ __launch_bounds__(256) void proj_qkv(
    const bf16* __restrict__ qc, const bf16* __restrict__ kc,
    const float* __restrict__ v, const bf16* __restrict__ WT,
    const float* __restrict__ bq, const float* __restrict__ bk,
    const float* __restrict__ bv, bf16* __restrict__ qh,
    bf16* __restrict__ kh, bf16* __restrict__ vt, float cscale)
{
  __shared__ bf16 sA[128 * 64];
  __shared__ bf16 sB[128 * 64];
  const int tid = threadIdx.x;
  const int wave = tid >> 6, lane = tid & 63;
  const int lr = lane & 15, quad = lane >> 4, kq = quad * 8;
  const int n0 = blockIdx.y * 128;
  const int mseg = blockIdx.x * 128;
  const int seg = mseg >> 13;
  const int m0 = mseg & 8191;
  const int wr = (wave >> 1) * 64, wc = (wave & 1) * 64;

  const float* bias = (seg == 0) ? bq : (seg == 1) ? bk : bv;
  const bf16* Bt = WT + (size_t)seg * (1 << 20);

  f32x4 acc[4][4];
#pragma unroll
  for (int i = 0; i < 4; i++)
#pragma unroll
    for (int j = 0; j < 4; j++)
#pragma unroll
      for (int e = 0; e < 4; e++) acc[i][j][e] = 0.f;

  const int srow = tid >> 3;
  const int scol = ((tid & 7) ^ (srow & 7)) * 8;
  const bf16* bPtr = Bt + (size_t)(n0 + srow) * 1024 + scol;
  bf16* sBd = sB + tid * 8;
  bf16* sAd = sA + tid * 8;
  const bf16* Ab = (seg == 1) ? kc : qc;
  const bf16* aPtr = Ab + (size_t)(m0 + srow) * 1024 + scol;
  const int ar = tid >> 1, ach2 = tid & 1;
  const float* vPtr = v + (size_t)(m0 + ar) * 1024 + ach2 * 32;

  if (seg < 2) {
    for (int k0 = 0; k0 < 1024; k0 += 64) {
      GLD(aPtr + k0,             sAd);
      GLD(aPtr + 32 * 1024 + k0, sAd + 2048);
      GLD(aPtr + 64 * 1024 + k0, sAd + 4096);
      GLD(aPtr + 96 * 1024 + k0, sAd + 6144);
      GLD(bPtr + k0,             sBd);
      GLD(bPtr + 32 * 1024 + k0, sBd + 2048);
      GLD(bPtr + 64 * 1024 + k0, sBd + 4096);
      GLD(bPtr + 96 * 1024 + k0, sBd + 6144);
      __syncthreads();
#pragma unroll
      for (int kk = 0; kk < 64; kk += 32) {
        bf16x8 af[4], bfr[4];
#pragma unroll
        for (int i = 0; i < 4; i++) {
          const int pos = (((kk >> 3) + quad) ^ (lr & 7)) * 8;
          af[i]  = *(const bf16x8*)(sA + (wr + i * 16 + lr) * 64 + pos);
          bfr[i] = *(const bf16x8*)(sB + (wc + i * 16 + lr) * 64 + pos);
        }
#pragma unroll
        for (int im = 0; im < 4; im++)
#pragma unroll
          for (int in = 0; in < 4; in++)
            acc[im][in] = mfma16(af[im], bfr[in], acc[im][in]);
      }
      __syncthreads();
    }
  } else {
    for (int k0 = 0; k0 < 1024; k0 += 64) {
      float4 f[8];
#pragma unroll
      for (int j = 0; j < 8; j++) f[j] = *(const float4*)(vPtr + k0 + j * 4);
      __syncthreads();  // all waves done with prev-iter sA/sB reads
      GLD(bPtr + k0,             sBd);
      GLD(bPtr + 32 * 1024 + k0, sBd + 2048);
      GLD(bPtr + 64 * 1024 + k0, sBd + 4096);
      GLD(bPtr + 96 * 1024 + k0, sBd + 6144);
#pragma unroll
      for (int j = 0; j < 4; j++) {
        bf16x8 p;
        p[0] = (bf16)f[2*j].x;   p[1] = (bf16)f[2*j].y;
        p[2] = (bf16)f[2*j].z;   p[3] = (bf16)f[2*j].w;
        p[4] = (bf16)f[2*j+1].x; p[5] = (bf16)f[2*j+1].y;
        p[6] = (bf16)f[2*j+1].z; p[7] = (bf16)f[2*j+1].w;
        const int cj = ach2 * 4 + j;
        *(bf16x8*)(sA + ar * 64 + ((cj ^ (ar & 7)) * 8)) = p;
      }
      __syncthreads();  // sA visible + GLD(B) drained (vmcnt)
#pragma unroll
      for (int kk = 0; kk < 64; kk += 32) {
        bf16x8 af[4], bfr[4];
#pragma unroll
        for (int i = 0; i < 4; i++) {
          const int pos = (((kk >> 3) + quad) ^ (lr & 7)) * 8;
          af[i]  = *(const bf16x8*)(sA + (wr + i * 16 + lr) * 64 + pos);
          bfr[i] = *(const bf16x8*)(sB + (wc + i * 16 + lr) * 64 + pos);
        }
#pragma unroll
        for (int im = 0; im < 4; im++)
#pragma unroll
          for (int in = 0; in < 4; in++)
            acc[im][in] = mfma16(af[im], bfr[in], acc[im][in]);
      }
    }
  }

  const int qd = quad * 4;
  float bv4[4];
#pragma unroll
  for (int in = 0; in < 4; in++) bv4[in] = bias[n0 + wc + in * 16 + lr];

  if (seg < 2) {
    bf16* C = (seg == 0) ? qh : kh;
    const float cmul = (seg == 0) ? cscale : 1.0f;
#pragma unroll
    for (int im = 0; im < 4; im++) {
      const int row = m0 + wr + im * 16 + qd;
#pragma unroll
      for (int in = 0; in < 4; in++) {
        const int col = n0 + wc + in * 16 + lr;
#pragma unroll
        for (int i = 0; i < 4; i++)
          C[(size_t)(row + i) * 1024 + col] = (bf16)((acc[im][in][i] + bv4[in]) * cmul);
      }
    }
  } else {
#pragma unroll
    for (int im = 0; im < 4; im++) {
      const int row = m0 + wr + im * 16 + qd;   // global s, multiple of 4
      const int b = row >> 10, sin = row & 1023;
#pragma unroll
      for (int in = 0; in < 4; in++) {
        const int col = n0 + wc + in * 16 + lr; // h*64+e
        const int h = col >> 6, e = col & 63;
        bf16x4 pk;
#pragma unroll
        for (int i = 0; i < 4; i++) pk[i] = (bf16)(acc[im][in][i] + bv4[in]);
        *(bf16x4*)(vt + (size_t)(b * 16 + h) * 65536 + e * 1024 + sin) = pk;
      }
    }
  }
}

// ---------------------------------------------------------------------------
// Final GEMM: out[8192,1024](fp32) = A(bf16) @ WoT^T + bo. BK=64, GLD +
// XOR swizzle, grid (64 m-fast, 8 n).
// ---------------------------------------------------------------------------
__global__ __launch_bounds__(256) void gemm_a16_c32(
    const bf16* __restrict__ A, const bf16* __restrict__ Bt,
    const float* __restrict__ bias, float* __restrict__ C)
{
  __shared__ bf16 sA[128 * 64];
  __shared__ bf16 sB[128 * 64];
  const int tid = threadIdx.x;
  const int wave = tid >> 6, lane = tid & 63;
  const int lr = lane & 15, quad = lane >> 4, kq = quad * 8;
  const int m0 = blockIdx.x * 128, n0 = blockIdx.y * 128;
  const int wr = (wave >> 1) * 64, wc = (wave & 1) * 64;

  f32x4 acc[4][4];
#pragma unroll
  for (int i = 0; i < 4; i++)
#pragma unroll
    for (int j = 0; j < 4; j++)
#pragma unroll
      for (int e = 0; e < 4; e++) acc[i][j][e] = 0.f;

  const int srow = tid >> 3;
  const int sc = ((tid & 7) ^ (srow & 7)) * 8;
  const bf16* aPtr = A + (size_t)(m0 + srow) * 1024 + sc;
  const bf16* bPtr = Bt + (size_t)(n0 + srow) * 1024 + sc;
  bf16* sAd = sA + tid * 8;
  bf16* sBd = sB + tid * 8;

  for (int k0 = 0; k0 < 1024; k0 += 64) {
    GLD(aPtr + k0,             sAd);
    GLD(aPtr + 32 * 1024 + k0, sAd + 2048);
    GLD(aPtr + 64 * 1024 + k0, sAd + 4096);
    GLD(aPtr + 96 * 1024 + k0, sAd + 6144);
    GLD(bPtr + k0,             sBd);
    GLD(bPtr + 32 * 1024 + k0, sBd + 2048);
    GLD(bPtr + 64 * 1024 + k0, sBd + 4096);
    GLD(bPtr + 96 * 1024 + k0, sBd + 6144);
    __syncthreads();
#pragma unroll
    for (int kk = 0; kk < 64; kk += 32) {
      bf16x8 af[4], bfr[4];
#pragma unroll
      for (int i = 0; i < 4; i++) {
        const int pos = (((kk >> 3) + quad) ^ (lr & 7)) * 8;
        af[i]  = *(const bf16x8*)(sA + (wr + i * 16 + lr) * 64 + pos);
        bfr[i] = *(const bf16x8*)(sB + (wc + i * 16 + lr) * 64 + pos);
      }
#pragma unroll
      for (int im = 0; im < 4; im++)
#pragma unroll
        for (int in = 0; in < 4; in++)
          acc[im][in] = mfma16(af[im], bfr[in], acc[im][in]);
    }
    __syncthreads();
  }

  const int qd = quad * 4;
  float bv4[4];
#pragma unroll
  for (int in = 0; in < 4; in++) bv4[in] = bias[n0 + wc + in * 16 + lr];
#pragma unroll
  for (int im = 0; im < 4; im++) {
    const int row = m0 + wr + im * 16 + qd;
#pragma unroll
    for (int in = 0; in < 4; in++) {
      const int col = n0 + wc + in * 16 + lr;
#pragma unroll
      for (int i = 0; i < 4; i++)
        C[(size_t)(row + i) * 1024 + col] = acc[im][in][i] + bv4[in];
    }
  }
}

// ---------------------------------------------------------------------------
// Flash attention per (b,h) — proven structure (84 us). Q pre-scaled ->
// exp2 domain, no running max. LDS rows padded to 72.
// O aliases Q (in-place: each block owns its exact (b,h,q-tile) slice),
// so Q/O are NOT __restrict__. grid: (16 h, 8 b, 8 qtile).
// ---------------------------------------------------------------------------
__global__ __launch_bounds__(256) void attn_k(
    const bf16* Q, const bf16* __restrict__ Kh,
    const bf16* __restrict__ Vt, bf16* O)
{
  __shared__ bf16 sK[64 * 72];
  __shared__ bf16 sV[64 * 72];
  __shared__ bf16 sP[128 * 72];
  const int h = blockIdx.x, b = blockIdx.y, q0 = blockIdx.z * 128;
  const int tid = threadIdx.x, wave = tid >> 6, lane = tid & 63;
  const int lr = lane & 15, quad = lane >> 4, kq = quad * 8;
  const int wq = wave * 32;

  const bf16* Qb = Q + (size_t)(b * 1024 + q0) * 1024 + h * 64;
  const bf16* Kb = Kh + (size_t)(b * 1024) * 1024 + h * 64;
  const bf16* Vb = Vt + (size_t)(b * 16 + h) * 65536;

  bf16x8 qf[2][2];
#pragma unroll
  for (int rg = 0; rg < 2; rg++)
#pragma unroll
    for (int ks = 0; ks < 2; ks++)
      qf[rg][ks] = *(const bf16x8*)(Qb + (wq + rg * 16 + lr) * 1024 + ks * 32 + kq);

  f32x4 o[2][4];
  float rsum[2][4];
#pragma unroll
  for (int rg = 0; rg < 2; rg++) {
#pragma unroll
    for (int et = 0; et < 4; et++)
#pragma unroll
      for (int e = 0; e < 4; e++) o[rg][et][e] = 0.f;
#pragma unroll
    for (int i = 0; i < 4; i++) rsum[rg][i] = 0.f;
  }

  const int r = tid >> 3;
  const int c = (tid & 7) * 8;

  for (int kv0 = 0; kv0 < 1024; kv0 += 64) {
    bf16x8 k1 = *(const bf16x8*)(Kb + (size_t)(kv0 + r) * 1024 + c);
    bf16x8 k2 = *(const bf16x8*)(Kb + (size_t)(kv0 + 32 + r) * 1024 + c);
    bf16x8 v1 = *(const bf16x8*)(Vb + (size_t)r * 1024 + kv0 + c);
    bf16x8 v2 = *(const bf16x8*)(Vb + (size_t)(32 + r) * 1024 + kv0 + c);
    __syncthreads();
    *(bf16x8*)(sK + r * 72 + c) = k1;
    *(bf16x8*)(sK + (32 + r) * 72 + c) = k2;
    *(bf16x8*)(sV + r * 72 + c) = v1;
    *(bf16x8*)(sV + (32 + r) * 72 + c) = v2;
    __syncthreads();

    f32x4 sc[2][4];
#pragma unroll
    for (int nt = 0; nt < 4; nt++) {
      bf16x8 kf0 = *(const bf16x8*)(sK + (nt * 16 + lr) * 72 + kq);
      bf16x8 kf1 = *(const bf16x8*)(sK + (nt * 16 + lr) * 72 + 32 + kq);
#pragma unroll
      for (int rg = 0; rg < 2; rg++) {
        f32x4 z;
#pragma unroll
        for (int e = 0; e < 4; e++) z[e] = 0.f;
        z = mfma16(qf[rg][0], kf0, z);
        z = mfma16(qf[rg][1], kf1, z);
        sc[rg][nt] = z;
      }
    }

#pragma unroll
    for (int rg = 0; rg < 2; rg++)
#pragma unroll
      for (int i = 0; i < 4; i++) {
        float p0 = exp2f(sc[rg][0][i]);
        float p1 = exp2f(sc[rg][1][i]);
        float p2 = exp2f(sc[rg][2][i]);
        float p3 = exp2f(sc[rg][3][i]);
        rsum[rg][i] += (p0 + p1) + (p2 + p3);
        const int prow = (wq + rg * 16 + quad * 4 + i) * 72;
        sP[prow + 0 * 16 + lr] = (bf16)p0;
        sP[prow + 1 * 16 + lr] = (bf16)p1;
        sP[prow + 2 * 16 + lr] = (bf16)p2;
        sP[prow + 3 * 16 + lr] = (bf16)p3;
      }
    __syncthreads();

#pragma unroll
    for (int et = 0; et < 4; et++) {
      bf16x8 vf0 = *(const bf16x8*)(sV + (et * 16 + lr) * 72 + kq);
      bf16x8 vf1 = *(const bf16x8*)(sV + (et * 16 + lr) * 72 + 32 + kq);
#pragma unroll
      for (int rg = 0; rg < 2; rg++) {
        bf16x8 pa = *(const bf16x8*)(sP + (wq + rg * 16 + lr) * 72 + kq);
        bf16x8 pb = *(const bf16x8*)(sP + (wq + rg * 16 + lr) * 72 + 32 + kq);
        o[rg][et] = mfma16(pa, vf0, o[rg][et]);
        o[rg][et] = mfma16(pb, vf1, o[rg][et]);
      }
    }
  }

#pragma unroll
  for (int rg = 0; rg < 2; rg++)
#pragma unroll
    for (int i = 0; i < 4; i++) {
      float rs = rsum[rg][i];
#pragma unroll
      for (int off = 1; off < 16; off <<= 1)
        rs += __shfl_xor(rs, off, 64);
      rsum[rg][i] = 1.f / rs;
    }

  bf16* Ob = O + (size_t)(b * 1024 + q0) * 1024 + h * 64;
#pragma unroll
  for (int rg = 0; rg < 2; rg++)
#pragma unroll
    for (int i = 0; i < 4; i++) {
      const int row = wq + rg * 16 + quad * 4 + i;
#pragma unroll
      for (int et = 0; et < 4; et++)
        Ob[row * 1024 + et * 16 + lr] = (bf16)(o[rg][et][i] * rsum[rg][i]);
    }
}

// ---------------------------------------------------------------------------
extern "C" void kernel_launch(void* const* d_in, const int* in_sizes, int n_in,
                              void* d_out, int out_size, void* d_ws, size_t ws_size,
                              hipStream_t stream)
{
  const float* q  = (const float*)d_in[0];
  const float* k  = (const float*)d_in[1];
  const float* v  = (const float*)d_in[2];
  const float* Wq = (const float*)d_in[3];
  const float* bq = (const float*)d_in[4];
  const float* Wk = (const float*)d_in[5];
  const float* bk = (const float*)d_in[6];
  const float* Wv = (const float*)d_in[7];
  const float* bv = (const float*)d_in[8];
  const float* Wo = (const float*)d_in[9];
  const float* bo = (const float*)d_in[10];
  float* out = (float*)d_out;
  bf16* ws = (bf16*)d_ws;

  const int MB = 1 << 20;
  // ws (56 MB, proven budget):
  bf16* WT  = ws;               // [3][1024][1024]
  bf16* qh  = ws + 3 * MB;      // [8192][1024]; attn writes O in-place here
  bf16* kh  = ws + 11 * MB;     // [8192][1024]
  bf16* vt  = ws + 19 * MB;     // [B*H][64 e][1024 s]
  bf16* WoT = ws + 27 * MB;     // [1024][1024]
  // d_out (32 MB) as scratch until the final GEMM overwrites it:
  bf16* qc  = (bf16*)d_out;             // 8M el
  bf16* kc  = (bf16*)d_out + 8 * MB;    // 8M el

  const float cscale = 0.1803368801111601f;  // (1/8)*log2(e), folded into qh

  dim3 tb(32, 8);
  wtrans3<<<dim3(32, 32, 3), tb, 0, stream>>>(Wq, Wk, Wv, WT);
  wtransO<<<dim3(32, 32), tb, 0, stream>>>(Wo, WoT);
  cast2<<<dim3(4096, 2), 256, 0, stream>>>(q, k, qc, kc);

  // fused projections: q,k via bf16 GLD; v via fp32 staging, output
  // directly in vt layout (no separate V-transpose dispatch)
  proj_qkv<<<dim3(192, 8), 256, 0, stream>>>(qc, kc, v, WT, bq, bk, bv,
                                             qh, kh, vt, cscale);

  attn_k<<<dim3(16, 8, 8), 256, 0, stream>>>(qh, kh, vt, qh);

  // out(fp32) = ctx(=qh) @ Wo + bo
  gemm_a16_c32<<<dim3(64, 8), 256, 0, stream>>>(qh, WoT, bo, out);
}

// Round 9
// 341.575 us; speedup vs baseline: 1.1612x; 1.0625x over previous
//
#include <hip/hip_runtime.h>
#include <hip/hip_bf16.h>
#include <stdint.h>

typedef __bf16 bf16;
typedef __attribute__((ext_vector_type(8))) __bf16 bf16x8;
typedef __attribute__((ext_vector_type(4))) __bf16 bf16x4;
typedef __attribute__((ext_vector_type(4))) float f32x4;

// async global->LDS, 16B per lane. LDS dest is linear: wave base + lane*16.
#define GLD(g, l) __builtin_amdgcn_global_load_lds( \
    (const __attribute__((address_space(1))) void*)(g), \
    (__attribute__((address_space(3))) void*)(l), 16, 0, 0)

__device__ __forceinline__ f32x4 mfma16(bf16x8 a, bf16x8 b, f32x4 c) {
  return __builtin_amdgcn_mfma_f32_16x16x32_bf16(a, b, c, 0, 0, 0);
}
__device__ __forceinline__ float fexp2(float x) {
  return __builtin_amdgcn_exp2f(x);
}

// ---------------------------------------------------------------------------
// Fused per-head weight transpose: W{q,k,v}[h][1024 d][64 e](fp32) ->
// WT[w][(h*64+e)][d](bf16). grid (32,32,3), block (32,8).
// ---------------------------------------------------------------------------
__global__ void wtrans3(const float* __restrict__ Wq, const float* __restrict__ Wk,
                        const float* __restrict__ Wv, bf16* __restrict__ WT)
{
  __shared__ bf16 t[32][33];
  const int w = blockIdx.z;
  const float* W = (w == 0) ? Wq : (w == 1) ? Wk : Wv;
  const int h = blockIdx.x >> 1;
  const int c0 = (blockIdx.x & 1) * 32;
  const int r0 = blockIdx.y * 32;
  const float* s = W + (size_t)h * 65536;
  bf16* d = WT + (size_t)w * (1 << 20) + (size_t)h * 65536;
  const int tx = threadIdx.x, ty = threadIdx.y;
#pragma unroll
  for (int i = 0; i < 32; i += 8)
    t[ty + i][tx] = (bf16)s[(r0 + ty + i) * 64 + c0 + tx];
  __syncthreads();
#pragma unroll
  for (int i = 0; i < 32; i += 8)
    d[(c0 + ty + i) * 1024 + r0 + tx] = t[tx][ty + i];
}

// ---------------------------------------------------------------------------
// Wo[k,n](fp32) -> WoT[n,k](bf16). grid (32,32), block (32,8).
// ---------------------------------------------------------------------------
__global__ void wtransO(const float* __restrict__ src, bf16* __restrict__ dst)
{
  __shared__ bf16 t[32][33];
  const int c0 = blockIdx.x * 32, r0 = blockIdx.y * 32;
  const int tx = threadIdx.x, ty = threadIdx.y;
#pragma unroll
  for (int i = 0; i < 32; i += 8)
    t[ty + i][tx] = (bf16)src[(r0 + ty + i) * 1024 + c0 + tx];
  __syncthreads();
#pragma unroll
  for (int i = 0; i < 32; i += 8)
    dst[(c0 + ty + i) * 1024 + r0 + tx] = t[tx][ty + i];
}

// ---------------------------------------------------------------------------
// fp32 -> bf16 cast for q and k in one dispatch. grid (4096, 2).
// ---------------------------------------------------------------------------
__global__ __launch_bounds__(256) void cast2(const float* __restrict__ q,
                                             const float* __restrict__ k,
                                             bf16* __restrict__ qc,
                                             bf16* __restrict__ kc)
{
  const float* s = blockIdx.y ? k : q;
  bf16* d = blockIdx.y ? kc : qc;
  const size_t i = ((size_t)blockIdx.x * 256 + threadIdx.x) * 8;
  float4 a = *(const float4*)(s + i);
  float4 b = *(const float4*)(s + i + 4);
  bf16x8 p;
  p[0] = (bf16)a.x; p[1] = (bf16)a.y; p[2] = (bf16)a.z; p[3] = (bf16)a.w;
  p[4] = (bf16)b.x; p[5] = (bf16)b.y; p[6] = (bf16)b.z; p[7] = (bf16)b.w;
  *(bf16x8*)(d + i) = p;
}

// ---------------------------------------------------------------------------
// Fused QKV projection, stacked-M (seg = q/k/v). 128x128 tile, BK=32,
// DOUBLE-BUFFERED LDS, ONE barrier per K-iter: the barrier's vmcnt(0) drain
// lands AFTER a full compute phase, so GLD latency is hidden (the fix for
// rounds 6-8's latency-bound 2-barrier loop).
// seg 0/1: A bf16 via GLD. seg 2: A fp32 reg-prefetch + cvt, B via GLD;
// epilogue writes vt[(b*16+h)*65536 + e*1024 + s] directly.
// grid (192 m-fast, 8 n): same-stripe blocks share XCD for A L2 reuse.
// ---------------------------------------------------------------------------
__global__ __launch_bounds__(256) void proj_qkv(
    const bf16* __restrict__ qc, const bf16* __restrict__ kc,
    const float* __restrict__ v, const bf16* __restrict__ WT,
    const float* __restrict__ bq, const float* __restrict__ bk,
    const float* __restrict__ bv, bf16* __restrict__ qh,
    bf16* __restrict__ kh, bf16* __restrict__ vt, float cscale)
{
  __shared__ bf16 S[16384];  // 32KB: buf p at p*8192 (A 4096 el | B 4096 el)
  const int tid = threadIdx.x;
  const int wave = tid >> 6, lane = tid & 63;
  const int lr = lane & 15, quad = lane >> 4, kq = quad * 8;
  const int n0 = blockIdx.y * 128;
  const int mseg = blockIdx.x * 128;
  const int seg = mseg >> 13;
  const int m0 = mseg & 8191;
  const int wr = (wave >> 1) * 64, wc = (wave & 1) * 64;

  const float* bias = (seg == 0) ? bq : (seg == 1) ? bk : bv;
  const bf16* Bt = WT + (size_t)seg * (1 << 20);

  f32x4 acc[4][4];
#pragma unroll
  for (int i = 0; i < 4; i++)
#pragma unroll
    for (int j = 0; j < 4; j++)
#pragma unroll
      for (int e = 0; e < 4; e++) acc[i][j][e] = 0.f;

  // GLD staging map (m97 layout): row=tid>>2 (+64 for batch 1), col=(tid&3)*8
  const int srow = tid >> 2;
  const int sko = (tid & 3) * 8;
  const bf16* bPtr = Bt + (size_t)(n0 + srow) * 1024 + sko;

  if (seg < 2) {
    const bf16* Ab = (seg == 1) ? kc : qc;
    const bf16* aPtr = Ab + (size_t)(m0 + srow) * 1024 + sko;
    // prologue: GLD k0=0 into buf 0
    GLD(aPtr,             S + tid * 8);
    GLD(aPtr + 64 * 1024, S + 2048 + tid * 8);
    GLD(bPtr,             S + 4096 + tid * 8);
    GLD(bPtr + 64 * 1024, S + 6144 + tid * 8);
    for (int it = 0; it < 32; ++it) {
      const int p = it & 1;
      bf16* buf = S + p * 8192;
      bf16* nbuf = S + (p ^ 1) * 8192;
      __syncthreads();  // drains GLDs for buf p; prev compute on nbuf done
      if (it + 1 < 32) {
        const int k0 = (it + 1) * 32;
        GLD(aPtr + k0,             nbuf + tid * 8);
        GLD(aPtr + 64 * 1024 + k0, nbuf + 2048 + tid * 8);
        GLD(bPtr + k0,             nbuf + 4096 + tid * 8);
        GLD(bPtr + 64 * 1024 + k0, nbuf + 6144 + tid * 8);
      }
      bf16x8 af[4], bfr[4];
#pragma unroll
      for (int i = 0; i < 4; i++) {
        af[i]  = *(const bf16x8*)(buf + (wr + i * 16 + lr) * 32 + kq);
        bfr[i] = *(const bf16x8*)(buf + 4096 + (wc + i * 16 + lr) * 32 + kq);
      }
#pragma unroll
      for (int im = 0; im < 4; im++)
#pragma unroll
        for (int in = 0; in < 4; in++)
          acc[im][in] = mfma16(af[im], bfr[in], acc[im][in]);
    }
  } else {
    // A fp32: row=tid>>1 (0..127), 16 cols at (tid&1)*16
    const int ar = tid >> 1, ac2 = (tid & 1) * 16;
    const float* vPtr = v + (size_t)(m0 + ar) * 1024 + ac2;
    float4 f[4];
#pragma unroll
    for (int j = 0; j < 4; j++) f[j] = *(const float4*)(vPtr + j * 4);
    // cvt + store A(0) into buf0 (no readers yet), GLD B(0) -> buf0
    {
      bf16x8 p0, p1;
      p0[0]=(bf16)f[0].x; p0[1]=(bf16)f[0].y; p0[2]=(bf16)f[0].z; p0[3]=(bf16)f[0].w;
      p0[4]=(bf16)f[1].x; p0[5]=(bf16)f[1].y; p0[6]=(bf16)f[1].z; p0[7]=(bf16)f[1].w;
      p1[0]=(bf16)f[2].x; p1[1]=(bf16)f[2].y; p1[2]=(bf16)f[2].z; p1[3]=(bf16)f[2].w;
      p1[4]=(bf16)f[3].x; p1[5]=(bf16)f[3].y; p1[6]=(bf16)f[3].z; p1[7]=(bf16)f[3].w;
      *(bf16x8*)(S + ar * 32 + ac2)     = p0;
      *(bf16x8*)(S + ar * 32 + ac2 + 8) = p1;
    }
    GLD(bPtr,             S + 4096 + tid * 8);
    GLD(bPtr + 64 * 1024, S + 6144 + tid * 8);
    for (int it = 0; it < 32; ++it) {
      const int p = it & 1;
      bf16* buf = S + p * 8192;
      bf16* nbuf = S + (p ^ 1) * 8192;
      __syncthreads();  // drains B-GLD buf p; A-stores visible; prev compute done
      const bool more = (it + 1 < 32);
      if (more) {
        const int k0 = (it + 1) * 32;
        GLD(bPtr + k0,             nbuf + 4096 + tid * 8);
        GLD(bPtr + 64 * 1024 + k0, nbuf + 6144 + tid * 8);
#pragma unroll
        for (int j = 0; j < 4; j++) f[j] = *(const float4*)(vPtr + k0 + j * 4);
      }
      bf16x8 af[4], bfr[4];
#pragma unroll
      for (int i = 0; i < 4; i++) {
        af[i]  = *(const bf16x8*)(buf + (wr + i * 16 + lr) * 32 + kq);
        bfr[i] = *(const bf16x8*)(buf + 4096 + (wc + i * 16 + lr) * 32 + kq);
      }
#pragma unroll
      for (int im = 0; im < 4; im++)
#pragma unroll
        for (int in = 0; in < 4; in++)
          acc[im][in] = mfma16(af[im], bfr[in], acc[im][in]);
      if (more) {  // cvt (f landed during compute) + store into buf p^1
        bf16x8 p0, p1;
        p0[0]=(bf16)f[0].x; p0[1]=(bf16)f[0].y; p0[2]=(bf16)f[0].z; p0[3]=(bf16)f[0].w;
        p0[4]=(bf16)f[1].x; p0[5]=(bf16)f[1].y; p0[6]=(bf16)f[1].z; p0[7]=(bf16)f[1].w;
        p1[0]=(bf16)f[2].x; p1[1]=(bf16)f[2].y; p1[2]=(bf16)f[2].z; p1[3]=(bf16)f[2].w;
        p1[4]=(bf16)f[3].x; p1[5]=(bf16)f[3].y; p1[6]=(bf16)f[3].z; p1[7]=(bf16)f[3].w;
        *(bf16x8*)(nbuf + ar * 32 + ac2)     = p0;
        *(bf16x8*)(nbuf + ar * 32 + ac2 + 8) = p1;
      }
    }
  }

  const int qd = quad * 4;
  float bv4[4];
#pragma unroll
  for (int in = 0; in < 4; in++) bv4[in] = bias[n0 + wc + in * 16 + lr];

  if (seg < 2) {
    bf16* C = (seg == 0) ? qh : kh;
    const float cmul = (seg == 0) ? cscale : 1.0f;
#pragma unroll
    for (int im = 0; im < 4; im++) {
      const int row = m0 + wr + im * 16 + qd;
#pragma unroll
      for (int in = 0; in < 4; in++) {
        const int col = n0 + wc + in * 16 + lr;
#pragma unroll
        for (int i = 0; i < 4; i++)
          C[(size_t)(row + i) * 1024 + col] = (bf16)((acc[im][in][i] + bv4[in]) * cmul);
      }
    }
  } else {
#pragma unroll
    for (int im = 0; im < 4; im++) {
      const int row = m0 + wr + im * 16 + qd;
      const int b = row >> 10, sin = row & 1023;
#pragma unroll
      for (int in = 0; in < 4; in++) {
        const int col = n0 + wc + in * 16 + lr;
        const int h = col >> 6, e = col & 63;
        bf16x4 pk;
#pragma unroll
        for (int i = 0; i < 4; i++) pk[i] = (bf16)(acc[im][in][i] + bv4[in]);
        *(bf16x4*)(vt + (size_t)(b * 16 + h) * 65536 + e * 1024 + sin) = pk;
      }
    }
  }
}

// ---------------------------------------------------------------------------
// Final GEMM: out[8192,1024](fp32) = A(bf16) @ WoT^T + bo.
// BK=32 double-buffered single-barrier loop (same as proj seg<2).
// grid (64 m-fast, 8 n).
// ---------------------------------------------------------------------------
__global__ __launch_bounds__(256) void gemm_a16_c32(
    const bf16* __restrict__ A, const bf16* __restrict__ Bt,
    const float* __restrict__ bias, float* __restrict__ C)
{
  __shared__ bf16 S[16384];
  const int tid = threadIdx.x;
  const int wave = tid >> 6, lane = tid & 63;
  const int lr = lane & 15, kq = ((lane >> 4)) * 8;
  const int m0 = blockIdx.x * 128, n0 = blockIdx.y * 128;
  const int wr = (wave >> 1) * 64, wc = (wave & 1) * 64;

  f32x4 acc[4][4];
#pragma unroll
  for (int i = 0; i < 4; i++)
#pragma unroll
    for (int j = 0; j < 4; j++)
#pragma unroll
      for (int e = 0; e < 4; e++) acc[i][j][e] = 0.f;

  const int srow = tid >> 2;
  const int sko = (tid & 3) * 8;
  const bf16* aPtr = A + (size_t)(m0 + srow) * 1024 + sko;
  const bf16* bPtr = Bt + (size_t)(n0 + srow) * 1024 + sko;

  GLD(aPtr,             S + tid * 8);
  GLD(aPtr + 64 * 1024, S + 2048 + tid * 8);
  GLD(bPtr,             S + 4096 + tid * 8);
  GLD(bPtr + 64 * 1024, S + 6144 + tid * 8);
  for (int it = 0; it < 32; ++it) {
    const int p = it & 1;
    bf16* buf = S + p * 8192;
    bf16* nbuf = S + (p ^ 1) * 8192;
    __syncthreads();
    if (it + 1 < 32) {
      const int k0 = (it + 1) * 32;
      GLD(aPtr + k0,             nbuf + tid * 8);
      GLD(aPtr + 64 * 1024 + k0, nbuf + 2048 + tid * 8);
      GLD(bPtr + k0,             nbuf + 4096 + tid * 8);
      GLD(bPtr + 64 * 1024 + k0, nbuf + 6144 + tid * 8);
    }
    bf16x8 af[4], bfr[4];
#pragma unroll
    for (int i = 0; i < 4; i++) {
      af[i]  = *(const bf16x8*)(buf + (wr + i * 16 + lr) * 32 + kq);
      bfr[i] = *(const bf16x8*)(buf + 4096 + (wc + i * 16 + lr) * 32 + kq);
    }
#pragma unroll
    for (int im = 0; im < 4; im++)
#pragma unroll
      for (int in = 0; in < 4; in++)
        acc[im][in] = mfma16(af[im], bfr[in], acc[im][in]);
  }

  const int qd = ((tid & 63) >> 4) * 4;
  float bv4[4];
#pragma unroll
  for (int in = 0; in < 4; in++) bv4[in] = bias[n0 + wc + in * 16 + lr];
#pragma unroll
  for (int im = 0; im < 4; im++) {
    const int row = m0 + wr + im * 16 + qd;
#pragma unroll
    for (int in = 0; in < 4; in++) {
      const int col = n0 + wc + in * 16 + lr;
#pragma unroll
      for (int i = 0; i < 4; i++)
        C[(size_t)(row + i) * 1024 + col] = acc[im][in][i] + bv4[in];
    }
  }
}

// ---------------------------------------------------------------------------
// Flash attention per (b,h). Q pre-scaled -> exp2 domain, no running max.
// LDS rows padded to 72. K/V REGISTER-PREFETCHED one KV-tile ahead: loads
// issue after barrier (b), drain at the sP barrier (~QK+softmax of cover).
// O aliases Q (in-place). grid: (16 h, 8 b, 8 qtile).
// ---------------------------------------------------------------------------
__global__ __launch_bounds__(256) void attn_k(
    const bf16* Q, const bf16* __restrict__ Kh,
    const bf16* __restrict__ Vt, bf16* O)
{
  __shared__ bf16 sK[64 * 72];
  __shared__ bf16 sV[64 * 72];
  __shared__ bf16 sP[128 * 72];
  const int h = blockIdx.x, b = blockIdx.y, q0 = blockIdx.z * 128;
  const int tid = threadIdx.x, wave = tid >> 6, lane = tid & 63;
  const int lr = lane & 15, quad = lane >> 4, kq = quad * 8;
  const int wq = wave * 32;

  const bf16* Qb = Q + (size_t)(b * 1024 + q0) * 1024 + h * 64;
  const bf16* Kb = Kh + (size_t)(b * 1024) * 1024 + h * 64;
  const bf16* Vb = Vt + (size_t)(b * 16 + h) * 65536;

  bf16x8 qf[2][2];
#pragma unroll
  for (int rg = 0; rg < 2; rg++)
#pragma unroll
    for (int ks = 0; ks < 2; ks++)
      qf[rg][ks] = *(const bf16x8*)(Qb + (wq + rg * 16 + lr) * 1024 + ks * 32 + kq);

  f32x4 o[2][4];
  float rsum[2][4];
#pragma unroll
  for (int rg = 0; rg < 2; rg++) {
#pragma unroll
    for (int et = 0; et < 4; et++)
#pragma unroll
      for (int e = 0; e < 4; e++) o[rg][et][e] = 0.f;
#pragma unroll
    for (int i = 0; i < 4; i++) rsum[rg][i] = 0.f;
  }

  const int r = tid >> 3;
  const int c = (tid & 7) * 8;

  // prefetch KV-tile 0
  bf16x8 k1 = *(const bf16x8*)(Kb + (size_t)r * 1024 + c);
  bf16x8 k2 = *(const bf16x8*)(Kb + (size_t)(32 + r) * 1024 + c);
  bf16x8 v1 = *(const bf16x8*)(Vb + (size_t)r * 1024 + c);
  bf16x8 v2 = *(const bf16x8*)(Vb + (size_t)(32 + r) * 1024 + c);

  for (int kv0 = 0; kv0 < 1024; kv0 += 64) {
    __syncthreads();
    *(bf16x8*)(sK + r * 72 + c) = k1;
    *(bf16x8*)(sK + (32 + r) * 72 + c) = k2;
    *(bf16x8*)(sV + r * 72 + c) = v1;
    *(bf16x8*)(sV + (32 + r) * 72 + c) = v2;
    __syncthreads();
    if (kv0 + 64 < 1024) {  // issue next-tile loads; drained at the sP barrier
      k1 = *(const bf16x8*)(Kb + (size_t)(kv0 + 64 + r) * 1024 + c);
      k2 = *(const bf16x8*)(Kb + (size_t)(kv0 + 96 + r) * 1024 + c);
      v1 = *(const bf16x8*)(Vb + (size_t)r * 1024 + kv0 + 64 + c);
      v2 = *(const bf16x8*)(Vb + (size_t)(32 + r) * 1024 + kv0 + 64 + c);
    }

    f32x4 sc[2][4];
#pragma unroll
    for (int nt = 0; nt < 4; nt++) {
      bf16x8 kf0 = *(const bf16x8*)(sK + (nt * 16 + lr) * 72 + kq);
      bf16x8 kf1 = *(const bf16x8*)(sK + (nt * 16 + lr) * 72 + 32 + kq);
#pragma unroll
      for (int rg = 0; rg < 2; rg++) {
        f32x4 z;
#pragma unroll
        for (int e = 0; e < 4; e++) z[e] = 0.f;
        z = mfma16(qf[rg][0], kf0, z);
        z = mfma16(qf[rg][1], kf1, z);
        sc[rg][nt] = z;
      }
    }

#pragma unroll
    for (int rg = 0; rg < 2; rg++)
#pragma unroll
      for (int i = 0; i < 4; i++) {
        float p0 = fexp2(sc[rg][0][i]);
        float p1 = fexp2(sc[rg][1][i]);
        float p2 = fexp2(sc[rg][2][i]);
        float p3 = fexp2(sc[rg][3][i]);
        rsum[rg][i] += (p0 + p1) + (p2 + p3);
        const int prow = (wq + rg * 16 + quad * 4 + i) * 72;
        sP[prow + 0 * 16 + lr] = (bf16)p0;
        sP[prow + 1 * 16 + lr] = (bf16)p1;
        sP[prow + 2 * 16 + lr] = (bf16)p2;
        sP[prow + 3 * 16 + lr] = (bf16)p3;
      }
    __syncthreads();

#pragma unroll
    for (int et = 0; et < 4; et++) {
      bf16x8 vf0 = *(const bf16x8*)(sV + (et * 16 + lr) * 72 + kq);
      bf16x8 vf1 = *(const bf16x8*)(sV + (et * 16 + lr) * 72 + 32 + kq);
#pragma unroll
      for (int rg = 0; rg < 2; rg++) {
        bf16x8 pa = *(const bf16x8*)(sP + (wq + rg * 16 + lr) * 72 + kq);
        bf16x8 pb = *(const bf16x8*)(sP + (wq + rg * 16 + lr) * 72 + 32 + kq);
        o[rg][et] = mfma16(pa, vf0, o[rg][et]);
        o[rg][et] = mfma16(pb, vf1, o[rg][et]);
      }
    }
  }

#pragma unroll
  for (int rg = 0; rg < 2; rg++)
#pragma unroll
    for (int i = 0; i < 4; i++) {
      float rs = rsum[rg][i];
#pragma unroll
      for (int off = 1; off < 16; off <<= 1)
        rs += __shfl_xor(rs, off, 64);
      rsum[rg][i] = 1.f / rs;
    }

  bf16* Ob = O + (size_t)(b * 1024 + q0) * 1024 + h * 64;
#pragma unroll
  for (int rg = 0; rg < 2; rg++)
#pragma unroll
    for (int i = 0; i < 4; i++) {
      const int row = wq + rg * 16 + quad * 4 + i;
#pragma unroll
      for (int et = 0; et < 4; et++)
        Ob[row * 1024 + et * 16 + lr] = (bf16)(o[rg][et][i] * rsum[rg][i]);
    }
}

// ---------------------------------------------------------------------------
extern "C" void kernel_launch(void* const* d_in, const int* in_sizes, int n_in,
                              void* d_out, int out_size, void* d_ws, size_t ws_size,
                              hipStream_t stream)
{
  const float* q  = (const float*)d_in[0];
  const float* k  = (const float*)d_in[1];
  const float* v  = (const float*)d_in[2];
  const float* Wq = (const float*)d_in[3];
  const float* bq = (const float*)d_in[4];
  const float* Wk = (const float*)d_in[5];
  const float* bk = (const float*)d_in[6];
  const float* Wv = (const float*)d_in[7];
  const float* bv = (const float*)d_in[8];
  const float* Wo = (const float*)d_in[9];
  const float* bo = (const float*)d_in[10];
  float* out = (float*)d_out;
  bf16* ws = (bf16*)d_ws;

  const int MB = 1 << 20;
  bf16* WT  = ws;               // [3][1024][1024]
  bf16* qh  = ws + 3 * MB;      // [8192][1024]; attn writes O in-place here
  bf16* kh  = ws + 11 * MB;     // [8192][1024]
  bf16* vt  = ws + 19 * MB;     // [B*H][64 e][1024 s]
  bf16* WoT = ws + 27 * MB;     // [1024][1024]  (ws total 56 MB)
  bf16* qc  = (bf16*)d_out;             // d_out as scratch (dead before final GEMM)
  bf16* kc  = (bf16*)d_out + 8 * MB;

  const float cscale = 0.1803368801111601f;  // (1/8)*log2(e), folded into qh

  dim3 tb(32, 8);
  wtrans3<<<dim3(32, 32, 3), tb, 0, stream>>>(Wq, Wk, Wv, WT);
  wtransO<<<dim3(32, 32), tb, 0, stream>>>(Wo, WoT);
  cast2<<<dim3(4096, 2), 256, 0, stream>>>(q, k, qc, kc);

  proj_qkv<<<dim3(192, 8), 256, 0, stream>>>(qc, kc, v, WT, bq, bk, bv,
                                             qh, kh, vt, cscale);

  attn_k<<<dim3(16, 8, 8), 256, 0, stream>>>(qh, kh, vt, qh);

  gemm_a16_c32<<<dim3(64, 8), 256, 0, stream>>>(qh, WoT, bo, out);
}